// Round 16
// baseline (402.340 us; speedup 1.0000x reference)
//
#include <hip/hip_runtime.h>
#include <hip/hip_bf16.h>
#include <stdint.h>

#define NN 8192
#define EE 32768
#define BB 256
#define DD 64
#define FIN 11
#define EIN 5
#define HH 128

typedef __attribute__((ext_vector_type(4))) float f32x4;
typedef __attribute__((ext_vector_type(8))) short bf16x8;

__device__ __forceinline__ float sigmoidf_(float x) { return 1.0f / (1.0f + expf(-x)); }

__device__ __forceinline__ void gload16(const void* g, void* l) {
    __builtin_amdgcn_global_load_lds(
        (const __attribute__((address_space(1))) unsigned int*)g,
        (__attribute__((address_space(3))) unsigned int*)l, 16, 0, 0);
}

// ---------------- merged setup: h1 | lin0 | castT | tw | prep | counts ----------------
__global__ __launch_bounds__(256) void k_setup(const float* __restrict__ x,
                                               const float* __restrict__ edge_attr,
                                               const float* __restrict__ lin0_w,
                                               const float* __restrict__ lin0_b,
                                               const float* __restrict__ nn1_w,
                                               const float* __restrict__ nn1_b,
                                               const float* __restrict__ nn2_w,
                                               const float* __restrict__ nn2b,
                                               const float* __restrict__ root_w,
                                               const float* __restrict__ whh,
                                               const float* __restrict__ bhh,
                                               const float* __restrict__ s2s_wih,
                                               const float* __restrict__ s2s_whh,
                                               const int* __restrict__ ei,
                                               const int* __restrict__ batch,
                                               __hip_bfloat16* __restrict__ h1,
                                               float* __restrict__ outN,
                                               __hip_bfloat16* __restrict__ nn2T,
                                               float* __restrict__ wihT,
                                               float* __restrict__ whhT,
                                               float* __restrict__ Bcat,
                                               float* __restrict__ bcat,
                                               int* __restrict__ deg,
                                               int* __restrict__ cnt) {
    const int bid = blockIdx.x, t = threadIdx.x;
    if (bid < 4096) {                        // h1 = relu(ea @ nn1.T + b) -> bf16, 4 k/thread
        int u = bid * 256 + t;               // over E*32
        int e = u >> 5, k0 = (u & 31) * 4;
        float ea0 = edge_attr[e * EIN + 0], ea1 = edge_attr[e * EIN + 1],
              ea2 = edge_attr[e * EIN + 2], ea3 = edge_attr[e * EIN + 3],
              ea4 = edge_attr[e * EIN + 4];
        ushort4 o;
#pragma unroll
        for (int kk = 0; kk < 4; kk++) {
            int k = k0 + kk;
            const float* wr = nn1_w + k * EIN;
            float a = nn1_b[k] + ea0 * wr[0] + ea1 * wr[1] + ea2 * wr[2] + ea3 * wr[3] + ea4 * wr[4];
            __hip_bfloat16 b = __float2bfloat16(fmaxf(a, 0.0f));
            ((ushort*)&o)[kk] = *(ushort*)&b;
        }
        *(ushort4*)((ushort*)h1 + (size_t)e * 128 + k0) = o;
    } else if (bid < 4608) {                 // lin0, 4 d/thread
        int u = (bid - 4096) * 256 + t;      // over N*16
        int n = u >> 4, d0 = (u & 15) * 4;
        float xv[FIN];
#pragma unroll
        for (int k = 0; k < FIN; k++) xv[k] = x[n * FIN + k];
        float4 o;
#pragma unroll
        for (int dd = 0; dd < 4; dd++) {
            int d = d0 + dd;
            const float* wr = lin0_w + d * FIN;
            float a = lin0_b[d];
#pragma unroll
            for (int k = 0; k < FIN; k++) a += xv[k] * wr[k];
            ((float*)&o)[dd] = fmaxf(a, 0.0f);
        }
        *(float4*)(outN + (size_t)n * 64 + d0) = o;
    } else if (bid < 4864) {                 // transpose-cast nn2_w -> nn2T bf16 [d][slot][f][8]
        int u = (bid - 4608) * 256 + t;      // 65536 16B-units
        int d = u >> 10, rem = u & 1023, slot = rem >> 6, f = rem & 63;
        const float* src = nn2_w + ((size_t)(d * 64 + f) * 128 + slot * 8);
        float4 v0 = *(const float4*)(src);
        float4 v1 = *(const float4*)(src + 4);
        union { bf16x8 v; ushort us[8]; } ov;
        __hip_bfloat16 b;
        b = __float2bfloat16(v0.x); ov.us[0] = *(ushort*)&b;
        b = __float2bfloat16(v0.y); ov.us[1] = *(ushort*)&b;
        b = __float2bfloat16(v0.z); ov.us[2] = *(ushort*)&b;
        b = __float2bfloat16(v0.w); ov.us[3] = *(ushort*)&b;
        b = __float2bfloat16(v1.x); ov.us[4] = *(ushort*)&b;
        b = __float2bfloat16(v1.y); ov.us[5] = *(ushort*)&b;
        b = __float2bfloat16(v1.z); ov.us[6] = *(ushort*)&b;
        b = __float2bfloat16(v1.w); ov.us[7] = *(ushort*)&b;
        *(bf16x8*)((ushort*)nn2T + (size_t)u * 8) = ov.v;
    } else if (bid < 5056) {                 // transpose s2s weights
        int i = (bid - 4864) * 256 + t;
        if (i < 256 * 128) {
            int j = i >> 7, k = i & 127;
            wihT[k * 256 + j] = s2s_wih[i];
        } else {
            int i2 = i - 256 * 128;
            if (i2 < 256 * 64) {
                int j = i2 >> 6, k = i2 & 63;
                whhT[k * 256 + j] = s2s_whh[i2];
            }
        }
    } else if (bid < 5136) {                 // prep Bcat[320][64] + bcat
        int i = (bid - 5056) * 256 + t;
        int r = i >> 6, c = i & 63;
        float v;
        if (r < 64) v = root_w[i];
        else if (r < 256) v = whh[(size_t)(r - 64) * 64 + c];
        else v = nn2b[c * 64 + (r - 256)];
        Bcat[i] = v;
        if (c == 0) bcat[r] = (r >= 64 && r < 256) ? bhh[r - 64] : 0.0f;
    } else {                                 // counts
        int i = (bid - 5136) * 256 + t;
        if (i < EE) atomicAdd(&deg[ei[EE + i]], 1);
        if (i < NN) atomicAdd(&cnt[batch[i]], 1);
    }
}

// ---------------- inv_deg + batch scan ----------------
__global__ __launch_bounds__(256) void k_invscan(const int* __restrict__ deg,
                                                 float* __restrict__ invd,
                                                 const int* __restrict__ cnt,
                                                 int* __restrict__ offs) {
    const int bid = blockIdx.x, t = threadIdx.x;
    if (bid < 32) {
        int n = bid * 256 + t;
        int d = deg[n];
        invd[n] = d > 0 ? 1.0f / (float)d : 0.0f;
    } else {
        __shared__ int s[256];
        s[t] = cnt[t];
        __syncthreads();
        for (int off = 1; off < 256; off <<= 1) {
            int v = (t >= off) ? s[t - off] : 0;
            __syncthreads();
            s[t] += v;
            __syncthreads();
        }
        offs[t + 1] = s[t];
        if (t == 0) offs[0] = 0;
    }
}

// ---------------- fused NNConv message pass: 128-edge tile, 8 waves (R11 geometry + setprio)
__global__ __launch_bounds__(512, 4) void k_wemsg(const __hip_bfloat16* __restrict__ h1,
                                                  const __hip_bfloat16* __restrict__ nn2T,
                                                  const float* __restrict__ outN,
                                                  const float* __restrict__ rgh,  // nodeB at col 256, stride 320
                                                  const int* __restrict__ ei,
                                                  const float* __restrict__ invd,
                                                  float* __restrict__ agg) {
    __shared__ ushort sB[2][64 * 128];   // 2 x 16 KB chunk dbuf (linear nn2T image)
    __shared__ float soT[32][128];       // 16 KB [d_local][e]
    __shared__ int sDst[128];
    __shared__ int sSrc[128];
    __shared__ float sIv[128];

    const int t = threadIdx.x;
    const int w = t >> 6, l = t & 63;
    const int q = l >> 4, l15 = l & 15;
    const int eh = w >> 2, fs = (w & 3) * 16;
    const int e0 = (blockIdx.x >> 1) * 128;
    const int dh = blockIdx.x & 1;
    const int cbase = dh * 32;

    // ---- prologue: gather out[src] window (transposed) + edge meta ----
    {
        int r = t >> 2, seg = t & 3;         // r in [0,128)
        int s_ = ei[e0 + r];
        const float* orow = outN + (size_t)s_ * 64 + dh * 32 + seg * 8;
        float4 v0 = *(const float4*)(orow);
        float4 v1 = *(const float4*)(orow + 4);
        int c0 = seg * 8;
        soT[c0 + 0][r] = v0.x;
        soT[c0 + 1][r] = v0.y;
        soT[c0 + 2][r] = v0.z;
        soT[c0 + 3][r] = v0.w;
        soT[c0 + 4][r] = v1.x;
        soT[c0 + 5][r] = v1.y;
        soT[c0 + 6][r] = v1.z;
        soT[c0 + 7][r] = v1.w;
        if (seg == 0) {
            int d_ = ei[EE + e0 + r];
            sDst[r] = d_;
            sIv[r] = invd[d_];
            sSrc[r] = s_;
        }
    }
    // ---- A fragments to registers: wave's 64 edges (4 tiles of 16), K=128 ----
    bf16x8 af[4][4];
#pragma unroll
    for (int mi = 0; mi < 4; mi++)
#pragma unroll
        for (int kk = 0; kk < 4; kk++)
            af[mi][kk] = *(const bf16x8*)(h1 + (size_t)(e0 + eh * 64 + mi * 16 + l15) * 128 + (kk * 4 + q) * 8);

    // ---- staging: 1024 16B-units per chunk, 512 threads -> 2 units/thread, linear ----
    const __hip_bfloat16* p0 = nn2T + (size_t)cbase * 8192 + (size_t)t * 8;
    const __hip_bfloat16* p1 = nn2T + (size_t)cbase * 8192 + (size_t)(512 + t) * 8;
    ushort* d0a = &sB[0][(w * 64) * 8];
    ushort* d0b = &sB[0][(512 + w * 64) * 8];
    ushort* d1a = &sB[1][(w * 64) * 8];
    ushort* d1b = &sB[1][(512 + w * 64) * 8];

    gload16(p0, d0a);
    gload16(p1, d0b);
    __syncthreads();

    float msg[4][4];
#pragma unroll
    for (int mi = 0; mi < 4; mi++)
#pragma unroll
        for (int j = 0; j < 4; j++) msg[mi][j] = 0.0f;

    // ds_read offsets: slot = kk*4+q, row f = fs+l15 -> stride-1 per quarter-wave
    const int rb = fs + l15;
    const int lo0 = ((0 * 4 + q) * 64 + rb) * 8;
    const int lo1 = ((1 * 4 + q) * 64 + rb) * 8;
    const int lo2 = ((2 * 4 + q) * 64 + rb) * 8;
    const int lo3 = ((3 * 4 + q) * 64 + rb) * 8;

    for (int dl = 0; dl < 32; ++dl) {
        const int cur = dl & 1;
        if (dl < 31) {   // stage next chunk into other buffer (latency overlaps compute)
            size_t off = (size_t)(dl + 1) * 8192;
            gload16(p0 + off, cur ? d0a : d1a);
            gload16(p1 + off, cur ? d0b : d1b);
        }
        const ushort* sbc = &sB[cur][0];
        f32x4 a0 = (f32x4)0.0f, a1 = (f32x4)0.0f, a2 = (f32x4)0.0f, a3 = (f32x4)0.0f;
        bf16x8 b0_ = *(const bf16x8*)&sbc[lo0];
        bf16x8 b1_ = *(const bf16x8*)&sbc[lo1];
        bf16x8 b2_ = *(const bf16x8*)&sbc[lo2];
        bf16x8 b3_ = *(const bf16x8*)&sbc[lo3];
        __builtin_amdgcn_s_setprio(1);
        {
            a0 = __builtin_amdgcn_mfma_f32_16x16x32_bf16(af[0][0], b0_, a0, 0, 0, 0);
            a1 = __builtin_amdgcn_mfma_f32_16x16x32_bf16(af[1][0], b0_, a1, 0, 0, 0);
            a2 = __builtin_amdgcn_mfma_f32_16x16x32_bf16(af[2][0], b0_, a2, 0, 0, 0);
            a3 = __builtin_amdgcn_mfma_f32_16x16x32_bf16(af[3][0], b0_, a3, 0, 0, 0);
            a0 = __builtin_amdgcn_mfma_f32_16x16x32_bf16(af[0][1], b1_, a0, 0, 0, 0);
            a1 = __builtin_amdgcn_mfma_f32_16x16x32_bf16(af[1][1], b1_, a1, 0, 0, 0);
            a2 = __builtin_amdgcn_mfma_f32_16x16x32_bf16(af[2][1], b1_, a2, 0, 0, 0);
            a3 = __builtin_amdgcn_mfma_f32_16x16x32_bf16(af[3][1], b1_, a3, 0, 0, 0);
            a0 = __builtin_amdgcn_mfma_f32_16x16x32_bf16(af[0][2], b2_, a0, 0, 0, 0);
            a1 = __builtin_amdgcn_mfma_f32_16x16x32_bf16(af[1][2], b2_, a1, 0, 0, 0);
            a2 = __builtin_amdgcn_mfma_f32_16x16x32_bf16(af[2][2], b2_, a2, 0, 0, 0);
            a3 = __builtin_amdgcn_mfma_f32_16x16x32_bf16(af[3][2], b2_, a3, 0, 0, 0);
            a0 = __builtin_amdgcn_mfma_f32_16x16x32_bf16(af[0][3], b3_, a0, 0, 0, 0);
            a1 = __builtin_amdgcn_mfma_f32_16x16x32_bf16(af[1][3], b3_, a1, 0, 0, 0);
            a2 = __builtin_amdgcn_mfma_f32_16x16x32_bf16(af[2][3], b3_, a2, 0, 0, 0);
            a3 = __builtin_amdgcn_mfma_f32_16x16x32_bf16(af[3][3], b3_, a3, 0, 0, 0);
        }
        __builtin_amdgcn_s_setprio(0);
        {
            f32x4 s0 = *(const f32x4*)&soT[dl][eh * 64 + 0 * 16 + q * 4];
            f32x4 s1 = *(const f32x4*)&soT[dl][eh * 64 + 1 * 16 + q * 4];
            f32x4 s2 = *(const f32x4*)&soT[dl][eh * 64 + 2 * 16 + q * 4];
            f32x4 s3 = *(const f32x4*)&soT[dl][eh * 64 + 3 * 16 + q * 4];
#pragma unroll
            for (int j = 0; j < 4; j++) {
                msg[0][j] += a0[j] * s0[j];
                msg[1][j] += a1[j] * s1[j];
                msg[2][j] += a2[j] * s2[j];
                msg[3][j] += a3[j] * s3[j];
            }
        }
        __syncthreads();   // all waves done with sB[cur]; staged prefetch drained
    }

    // ---- add nodeB bias (dh 0 only) and scatter with inv_deg ----
    const int fcol = fs + l15;
#pragma unroll
    for (int mi = 0; mi < 4; mi++) {
#pragma unroll
        for (int j = 0; j < 4; j++) {
            int er = eh * 64 + mi * 16 + q * 4 + j;
            float v = msg[mi][j];
            if (dh == 0) v += rgh[(size_t)sSrc[er] * 320 + 256 + fcol];
            atomicAdd(&agg[(size_t)sDst[er] * 64 + fcol], v * sIv[er]);
        }
    }
}

// ---------------- rgh = outN @ Bcat.T + bcat  [N][320]; also zeroes agg ----------------
__global__ __launch_bounds__(256) void k_rgh(const float* __restrict__ A,
                                             const float* __restrict__ Bm,
                                             const float* __restrict__ bias,
                                             float* __restrict__ C,
                                             float* __restrict__ aggz) {
    const int tid = threadIdx.x;
    const int bx = blockIdx.x, by = blockIdx.y;   // grid (5, 128)
    {
        int bid = by * 5 + bx;
        if (bid < 512) {
            float4 z; z.x = z.y = z.z = z.w = 0.0f;
            *(float4*)(aggz + (size_t)bid * 1024 + tid * 4) = z;
        }
    }
    __shared__ float sA[64 * 68];
    __shared__ float sB[64 * 68];
    const float* Ab = A + (size_t)by * 64 * 64;
    const float* Bb = Bm + (size_t)bx * 64 * 64;
    for (int fi = tid; fi < 64 * 16; fi += 256) {
        int r = fi >> 4, c = (fi & 15) * 4;
        *(float4*)&sA[r * 68 + c] = *(const float4*)(Ab + (size_t)r * 64 + c);
        *(float4*)&sB[r * 68 + c] = *(const float4*)(Bb + (size_t)r * 64 + c);
    }
    __syncthreads();
    const int tx = tid & 15, ty = tid >> 4;
    float acc[4][4];
#pragma unroll
    for (int i = 0; i < 4; i++)
#pragma unroll
        for (int j = 0; j < 4; j++) acc[i][j] = 0.0f;
    for (int k = 0; k < 64; k += 4) {
        float4 av[4], bv[4];
#pragma unroll
        for (int i = 0; i < 4; i++) av[i] = *(const float4*)&sA[(ty + 16 * i) * 68 + k];
#pragma unroll
        for (int j = 0; j < 4; j++) bv[j] = *(const float4*)&sB[(tx + 16 * j) * 68 + k];
#pragma unroll
        for (int i = 0; i < 4; i++)
#pragma unroll
            for (int j = 0; j < 4; j++) {
                acc[i][j] += av[i].x * bv[j].x;
                acc[i][j] += av[i].y * bv[j].y;
                acc[i][j] += av[i].z * bv[j].z;
                acc[i][j] += av[i].w * bv[j].w;
            }
    }
#pragma unroll
    for (int i = 0; i < 4; i++) {
        size_t row = (size_t)by * 64 + ty + 16 * i;
#pragma unroll
        for (int j = 0; j < 4; j++) {
            int col = bx * 64 + tx + 16 * j;
            C[row * 320 + col] = acc[i][j] + bias[col];
        }
    }
}

// ---------------- fused gx GEMM + GRU, 16-row tiles (grid 512, 2 blocks/CU) ----------------
__global__ __launch_bounds__(256) void k_gxgru(const float* __restrict__ agg,
                                               const float* __restrict__ rgh,
                                               const float* __restrict__ cb,
                                               const float* __restrict__ wih,   // gru_w_ih [192][64]
                                               const float* __restrict__ bih,
                                               float* __restrict__ outN) {
    __shared__ float sA[16 * 68];
    __shared__ float sB[192 * 68];
    const int t = threadIdx.x;
    const int by = blockIdx.x;                    // 512 blocks x 16 rows
    {   // stage m = relu(agg + rootC + cb): 16x16 float4 units = 256 = one per thread
        int r = t >> 4, c = (t & 15) * 4;
        float4 av = *(const float4*)(agg + (size_t)(by * 16 + r) * 64 + c);
        float4 rv = *(const float4*)(rgh + (size_t)(by * 16 + r) * 320 + c);
        float4 cv = *(const float4*)(cb + c);
        float4 m;
        m.x = fmaxf(av.x + rv.x + cv.x, 0.0f);
        m.y = fmaxf(av.y + rv.y + cv.y, 0.0f);
        m.z = fmaxf(av.z + rv.z + cv.z, 0.0f);
        m.w = fmaxf(av.w + rv.w + cv.w, 0.0f);
        *(float4*)&sA[r * 68 + c] = m;
    }
    for (int fi = t; fi < 192 * 16; fi += 256) {
        int r = fi >> 4, c = (fi & 15) * 4;
        *(float4*)&sB[r * 68 + c] = *(const float4*)(wih + (size_t)r * 64 + c);
    }
    __syncthreads();
    const int tx = t & 15, ty = t >> 4;           // ty = row in [0,16)
    float acc[3][4];
#pragma unroll
    for (int cx = 0; cx < 3; cx++)
#pragma unroll
        for (int j = 0; j < 4; j++) acc[cx][j] = 0.0f;
    for (int k = 0; k < 64; k += 4) {
        float4 av = *(const float4*)&sA[ty * 68 + k];
#pragma unroll
        for (int cx = 0; cx < 3; cx++) {
#pragma unroll
            for (int j = 0; j < 4; j++) {
                float4 bv = *(const float4*)&sB[(cx * 64 + tx + 16 * j) * 68 + k];
                acc[cx][j] += av.x * bv.x + av.y * bv.y + av.z * bv.z + av.w * bv.w;
            }
        }
    }
    {
        int n = by * 16 + ty;
        const float* ghr = rgh + (size_t)n * 320 + 64;
#pragma unroll
        for (int j = 0; j < 4; j++) {
            int d = tx + 16 * j;
            float r = sigmoidf_(acc[0][j] + bih[d] + ghr[d]);
            float z = sigmoidf_(acc[1][j] + bih[64 + d] + ghr[64 + d]);
            float nn_ = tanhf(acc[2][j] + bih[128 + d] + r * ghr[128 + d]);
            float hp = outN[(size_t)n * 64 + d];
            outN[(size_t)n * 64 + d] = (1.0f - z) * nn_ + z * hp;
        }
    }
}

// ---------------- fused Set2Set (3 steps) + head: one block per graph ----------------
__global__ __launch_bounds__(256) void k_s2sall(const float* __restrict__ outN,
                                                const int* __restrict__ offs,
                                                const float* __restrict__ wihT,
                                                const float* __restrict__ whhT,
                                                const float* __restrict__ bih,
                                                const float* __restrict__ bhh,
                                                const float* __restrict__ lin1_w,
                                                const float* __restrict__ lin1_b,
                                                const float* __restrict__ lin2_w,
                                                const float* __restrict__ lin2_b,
                                                float* __restrict__ earr,
                                                float* __restrict__ y) {
    const int b = blockIdx.x, t = threadIdx.x;
    const int w = t >> 6, l = t & 63;
    __shared__ float qs[128], qhL[64], qcL[64], gates[256];
    __shared__ float red[8];
    __shared__ float rpart[4][64];
    __shared__ float hbuf[64];
    const int s0 = offs[b], s1 = offs[b + 1];
    if (t < 128) qs[t] = 0.0f;
    if (t < 64) { qhL[t] = 0.0f; qcL[t] = 0.0f; }
    __syncthreads();

    for (int st = 0; st < 3; st++) {
        float g = bih[t] + bhh[t];
        for (int k = 0; k < 128; k++) g += qs[k] * wihT[k * 256 + t];
        for (int k = 0; k < 64; k++) g += qhL[k] * whhT[k * 256 + t];
        gates[t] = g;
        __syncthreads();
        if (t < 64) {
            float gi = gates[t], gf = gates[64 + t], gg = gates[128 + t], go = gates[192 + t];
            float c = sigmoidf_(gf) * qcL[t] + sigmoidf_(gi) * tanhf(gg);
            qcL[t] = c;
            qhL[t] = sigmoidf_(go) * tanhf(c);
        }
        __syncthreads();
        float mx = -INFINITY;
        for (int i = s0 + w; i < s1; i += 4) {
            float p = outN[(size_t)i * 64 + l] * qhL[l];
#pragma unroll
            for (int o = 32; o > 0; o >>= 1) p += __shfl_xor(p, o, 64);
            if (l == 0) earr[i] = p;
            mx = fmaxf(mx, p);
        }
        if (l == 0) red[w] = mx;
        __syncthreads();
        mx = fmaxf(fmaxf(red[0], red[1]), fmaxf(red[2], red[3]));
        if (!isfinite(mx)) mx = 0.0f;
        float sm = 0.0f, racc = 0.0f;
        for (int i = s0 + w; i < s1; i += 4) {
            float a = expf(earr[i] - mx);
            sm += a;
            racc += a * outN[(size_t)i * 64 + l];
        }
        rpart[w][l] = racc;
        if (l == 0) red[4 + w] = sm;
        __syncthreads();
        float smT = fmaxf(red[4] + red[5] + red[6] + red[7], 1e-12f);
        if (t < 64) {
            float r = (rpart[0][t] + rpart[1][t] + rpart[2][t] + rpart[3][t]) / smT;
            qs[t] = qhL[t];
            qs[64 + t] = r;
        }
        __syncthreads();
    }
    if (t < 64) {
        float h = lin1_b[t];
        for (int k = 0; k < 128; k++) h += qs[k] * lin1_w[t * 128 + k];
        hbuf[t] = fmaxf(h, 0.0f) * lin2_w[t];
    }
    __syncthreads();
    if (w == 0) {
        float p = hbuf[l];
#pragma unroll
        for (int o = 32; o > 0; o >>= 1) p += __shfl_xor(p, o, 64);
        if (l == 0) y[b] = p + lin2_b[0];
    }
}

extern "C" void kernel_launch(void* const* d_in, const int* in_sizes, int n_in,
                              void* d_out, int out_size, void* d_ws, size_t ws_size,
                              hipStream_t stream) {
    const float* x = (const float*)d_in[0];
    const float* edge_attr = (const float*)d_in[1];
    const float* lin0_w = (const float*)d_in[2];
    const float* lin0_b = (const float*)d_in[3];
    const float* nn1_w = (const float*)d_in[4];
    const float* nn1_b = (const float*)d_in[5];
    const float* nn2_w = (const float*)d_in[6];
    const float* nn2_b = (const float*)d_in[7];
    const float* root_w = (const float*)d_in[8];
    const float* conv_b = (const float*)d_in[9];
    const float* gru_w_ih = (const float*)d_in[10];
    const float* gru_w_hh = (const float*)d_in[11];
    const float* gru_b_ih = (const float*)d_in[12];
    const float* gru_b_hh = (const float*)d_in[13];
    const float* s2s_w_ih = (const float*)d_in[14];
    const float* s2s_w_hh = (const float*)d_in[15];
    const float* s2s_b_ih = (const float*)d_in[16];
    const float* s2s_b_hh = (const float*)d_in[17];
    const float* lin1_w = (const float*)d_in[18];
    const float* lin1_b = (const float*)d_in[19];
    const float* lin2_w = (const float*)d_in[20];
    const float* lin2_b = (const float*)d_in[21];
    const int* ei = (const int*)d_in[22];
    const int* batch = (const int*)d_in[23];
    float* outp = (float*)d_out;

    char* w = (char*)d_ws;
    auto carve = [&](size_t bytes) { char* p = w; w += (bytes + 255) & ~(size_t)255; return p; };
    __hip_bfloat16* nn2T = (__hip_bfloat16*)carve((size_t)4096 * 128 * 2);
    float* outN = (float*)carve((size_t)NN * 64 * 4);
    __hip_bfloat16* h1 = (__hip_bfloat16*)carve((size_t)EE * 128 * 2);
    int* deg = (int*)carve(NN * 4);
    float* invd = (float*)carve(NN * 4);
    float* agg = (float*)carve((size_t)NN * 64 * 4);
    float* rgh = (float*)carve((size_t)NN * 320 * 4);
    float* Bcat = (float*)carve((size_t)320 * 64 * 4);
    float* bcat = (float*)carve(320 * 4);
    float* wihT = (float*)carve((size_t)128 * 256 * 4);
    float* whhT = (float*)carve((size_t)64 * 256 * 4);
    float* earr = (float*)carve(NN * 4);
    int* cnt = (int*)carve(256 * 4);
    int* offs = (int*)carve(257 * 4);

    hipMemsetAsync(deg, 0, NN * 4, stream);
    hipMemsetAsync(cnt, 0, 256 * 4, stream);

    k_setup<<<5264, 256, 0, stream>>>(x, edge_attr, lin0_w, lin0_b, nn1_w, nn1_b,
                                      nn2_w, nn2_b, root_w, gru_w_hh, gru_b_hh,
                                      s2s_w_ih, s2s_w_hh, ei, batch,
                                      h1, outN, nn2T, wihT, whhT, Bcat, bcat, deg, cnt);
    k_invscan<<<33, 256, 0, stream>>>(deg, invd, cnt, offs);

    for (int it = 0; it < 3; it++) {
        k_rgh<<<dim3(5, NN / 64), 256, 0, stream>>>(outN, Bcat, bcat, rgh, agg);
        k_wemsg<<<EE / 64, 512, 0, stream>>>(h1, nn2T, outN, rgh, ei, invd, agg);
        k_gxgru<<<NN / 16, 256, 0, stream>>>(agg, rgh, conv_b, gru_w_ih, gru_b_ih, outN);
    }

    k_s2sall<<<BB, 256, 0, stream>>>(outN, offs, wihT, whhT, s2s_b_ih, s2s_b_hh,
                                     lin1_w, lin1_b, lin2_w, lin2_b, earr, outp);
}

// Round 17
// 293.305 us; speedup vs baseline: 1.3717x; 1.3717x over previous
//
#include <hip/hip_runtime.h>
#include <hip/hip_bf16.h>
#include <stdint.h>

#define NN 8192
#define EE 32768
#define BB 256
#define DD 64
#define FIN 11
#define EIN 5
#define HH 128

typedef __attribute__((ext_vector_type(4))) float f32x4;
typedef __attribute__((ext_vector_type(8))) short bf16x8;

__device__ __forceinline__ float sigmoidf_(float x) { return 1.0f / (1.0f + expf(-x)); }

__device__ __forceinline__ void gload16(const void* g, void* l) {
    __builtin_amdgcn_global_load_lds(
        (const __attribute__((address_space(1))) unsigned int*)g,
        (__attribute__((address_space(3))) unsigned int*)l, 16, 0, 0);
}

// ---------------- merged setup: h1 | lin0 | castT | tw | prep | counts ----------------
__global__ __launch_bounds__(256) void k_setup(const float* __restrict__ x,
                                               const float* __restrict__ edge_attr,
                                               const float* __restrict__ lin0_w,
                                               const float* __restrict__ lin0_b,
                                               const float* __restrict__ nn1_w,
                                               const float* __restrict__ nn1_b,
                                               const float* __restrict__ nn2_w,
                                               const float* __restrict__ nn2b,
                                               const float* __restrict__ root_w,
                                               const float* __restrict__ whh,
                                               const float* __restrict__ bhh,
                                               const float* __restrict__ s2s_wih,
                                               const float* __restrict__ s2s_whh,
                                               const int* __restrict__ ei,
                                               const int* __restrict__ batch,
                                               __hip_bfloat16* __restrict__ h1,
                                               float* __restrict__ outN,
                                               __hip_bfloat16* __restrict__ nn2T,
                                               float* __restrict__ wihT,
                                               float* __restrict__ whhT,
                                               float* __restrict__ Bcat,
                                               float* __restrict__ bcat,
                                               int* __restrict__ deg,
                                               int* __restrict__ cnt) {
    const int bid = blockIdx.x, t = threadIdx.x;
    if (bid < 4096) {                        // h1 = relu(ea @ nn1.T + b) -> bf16, 4 k/thread
        int u = bid * 256 + t;               // over E*32
        int e = u >> 5, k0 = (u & 31) * 4;
        float ea0 = edge_attr[e * EIN + 0], ea1 = edge_attr[e * EIN + 1],
              ea2 = edge_attr[e * EIN + 2], ea3 = edge_attr[e * EIN + 3],
              ea4 = edge_attr[e * EIN + 4];
        ushort4 o;
#pragma unroll
        for (int kk = 0; kk < 4; kk++) {
            int k = k0 + kk;
            const float* wr = nn1_w + k * EIN;
            float a = nn1_b[k] + ea0 * wr[0] + ea1 * wr[1] + ea2 * wr[2] + ea3 * wr[3] + ea4 * wr[4];
            __hip_bfloat16 b = __float2bfloat16(fmaxf(a, 0.0f));
            ((ushort*)&o)[kk] = *(ushort*)&b;
        }
        *(ushort4*)((ushort*)h1 + (size_t)e * 128 + k0) = o;
    } else if (bid < 4608) {                 // lin0, 4 d/thread
        int u = (bid - 4096) * 256 + t;      // over N*16
        int n = u >> 4, d0 = (u & 15) * 4;
        float xv[FIN];
#pragma unroll
        for (int k = 0; k < FIN; k++) xv[k] = x[n * FIN + k];
        float4 o;
#pragma unroll
        for (int dd = 0; dd < 4; dd++) {
            int d = d0 + dd;
            const float* wr = lin0_w + d * FIN;
            float a = lin0_b[d];
#pragma unroll
            for (int k = 0; k < FIN; k++) a += xv[k] * wr[k];
            ((float*)&o)[dd] = fmaxf(a, 0.0f);
        }
        *(float4*)(outN + (size_t)n * 64 + d0) = o;
    } else if (bid < 4864) {                 // transpose-cast nn2_w -> nn2T bf16 [d][slot][f][8]
        int u = (bid - 4608) * 256 + t;      // 65536 16B-units
        int d = u >> 10, rem = u & 1023, slot = rem >> 6, f = rem & 63;
        const float* src = nn2_w + ((size_t)(d * 64 + f) * 128 + slot * 8);
        float4 v0 = *(const float4*)(src);
        float4 v1 = *(const float4*)(src + 4);
        union { bf16x8 v; ushort us[8]; } ov;
        __hip_bfloat16 b;
        b = __float2bfloat16(v0.x); ov.us[0] = *(ushort*)&b;
        b = __float2bfloat16(v0.y); ov.us[1] = *(ushort*)&b;
        b = __float2bfloat16(v0.z); ov.us[2] = *(ushort*)&b;
        b = __float2bfloat16(v0.w); ov.us[3] = *(ushort*)&b;
        b = __float2bfloat16(v1.x); ov.us[4] = *(ushort*)&b;
        b = __float2bfloat16(v1.y); ov.us[5] = *(ushort*)&b;
        b = __float2bfloat16(v1.z); ov.us[6] = *(ushort*)&b;
        b = __float2bfloat16(v1.w); ov.us[7] = *(ushort*)&b;
        *(bf16x8*)((ushort*)nn2T + (size_t)u * 8) = ov.v;
    } else if (bid < 5056) {                 // transpose s2s weights
        int i = (bid - 4864) * 256 + t;
        if (i < 256 * 128) {
            int j = i >> 7, k = i & 127;
            wihT[k * 256 + j] = s2s_wih[i];
        } else {
            int i2 = i - 256 * 128;
            if (i2 < 256 * 64) {
                int j = i2 >> 6, k = i2 & 63;
                whhT[k * 256 + j] = s2s_whh[i2];
            }
        }
    } else if (bid < 5136) {                 // prep Bcat[320][64] + bcat
        int i = (bid - 5056) * 256 + t;
        int r = i >> 6, c = i & 63;
        float v;
        if (r < 64) v = root_w[i];
        else if (r < 256) v = whh[(size_t)(r - 64) * 64 + c];
        else v = nn2b[c * 64 + (r - 256)];
        Bcat[i] = v;
        if (c == 0) bcat[r] = (r >= 64 && r < 256) ? bhh[r - 64] : 0.0f;
    } else {                                 // counts
        int i = (bid - 5136) * 256 + t;
        if (i < EE) atomicAdd(&deg[ei[EE + i]], 1);
        if (i < NN) atomicAdd(&cnt[batch[i]], 1);
    }
}

// ---------------- inv_deg + batch scan ----------------
__global__ __launch_bounds__(256) void k_invscan(const int* __restrict__ deg,
                                                 float* __restrict__ invd,
                                                 const int* __restrict__ cnt,
                                                 int* __restrict__ offs) {
    const int bid = blockIdx.x, t = threadIdx.x;
    if (bid < 32) {
        int n = bid * 256 + t;
        int d = deg[n];
        invd[n] = d > 0 ? 1.0f / (float)d : 0.0f;
    } else {
        __shared__ int s[256];
        s[t] = cnt[t];
        __syncthreads();
        for (int off = 1; off < 256; off <<= 1) {
            int v = (t >= off) ? s[t - off] : 0;
            __syncthreads();
            s[t] += v;
            __syncthreads();
        }
        offs[t + 1] = s[t];
        if (t == 0) offs[0] = 0;
    }
}

// ---------------- fused NNConv message pass: 128-edge tile, 8 waves (R11 geometry + setprio)
__global__ __launch_bounds__(512, 4) void k_wemsg(const __hip_bfloat16* __restrict__ h1,
                                                  const __hip_bfloat16* __restrict__ nn2T,
                                                  const float* __restrict__ outN,
                                                  const float* __restrict__ rgh,  // nodeB at col 256, stride 320
                                                  const int* __restrict__ ei,
                                                  const float* __restrict__ invd,
                                                  float* __restrict__ agg) {
    __shared__ ushort sB[2][64 * 128];   // 2 x 16 KB chunk dbuf (linear nn2T image)
    __shared__ float soT[32][128];       // 16 KB [d_local][e]
    __shared__ int sDst[128];
    __shared__ int sSrc[128];
    __shared__ float sIv[128];

    const int t = threadIdx.x;
    const int w = t >> 6, l = t & 63;
    const int q = l >> 4, l15 = l & 15;
    const int eh = w >> 2, fs = (w & 3) * 16;
    const int e0 = (blockIdx.x >> 1) * 128;
    const int dh = blockIdx.x & 1;
    const int cbase = dh * 32;

    // ---- prologue: gather out[src] window (transposed) + edge meta ----
    {
        int r = t >> 2, seg = t & 3;         // r in [0,128)
        int s_ = ei[e0 + r];
        const float* orow = outN + (size_t)s_ * 64 + dh * 32 + seg * 8;
        float4 v0 = *(const float4*)(orow);
        float4 v1 = *(const float4*)(orow + 4);
        int c0 = seg * 8;
        soT[c0 + 0][r] = v0.x;
        soT[c0 + 1][r] = v0.y;
        soT[c0 + 2][r] = v0.z;
        soT[c0 + 3][r] = v0.w;
        soT[c0 + 4][r] = v1.x;
        soT[c0 + 5][r] = v1.y;
        soT[c0 + 6][r] = v1.z;
        soT[c0 + 7][r] = v1.w;
        if (seg == 0) {
            int d_ = ei[EE + e0 + r];
            sDst[r] = d_;
            sIv[r] = invd[d_];
            sSrc[r] = s_;
        }
    }
    // ---- A fragments to registers: wave's 64 edges (4 tiles of 16), K=128 ----
    bf16x8 af[4][4];
#pragma unroll
    for (int mi = 0; mi < 4; mi++)
#pragma unroll
        for (int kk = 0; kk < 4; kk++)
            af[mi][kk] = *(const bf16x8*)(h1 + (size_t)(e0 + eh * 64 + mi * 16 + l15) * 128 + (kk * 4 + q) * 8);

    // ---- staging: 1024 16B-units per chunk, 512 threads -> 2 units/thread, linear ----
    const __hip_bfloat16* p0 = nn2T + (size_t)cbase * 8192 + (size_t)t * 8;
    const __hip_bfloat16* p1 = nn2T + (size_t)cbase * 8192 + (size_t)(512 + t) * 8;
    ushort* d0a = &sB[0][(w * 64) * 8];
    ushort* d0b = &sB[0][(512 + w * 64) * 8];
    ushort* d1a = &sB[1][(w * 64) * 8];
    ushort* d1b = &sB[1][(512 + w * 64) * 8];

    gload16(p0, d0a);
    gload16(p1, d0b);
    __syncthreads();

    float msg[4][4];
#pragma unroll
    for (int mi = 0; mi < 4; mi++)
#pragma unroll
        for (int j = 0; j < 4; j++) msg[mi][j] = 0.0f;

    // ds_read offsets: slot = kk*4+q, row f = fs+l15 -> stride-1 per quarter-wave
    const int rb = fs + l15;
    const int lo0 = ((0 * 4 + q) * 64 + rb) * 8;
    const int lo1 = ((1 * 4 + q) * 64 + rb) * 8;
    const int lo2 = ((2 * 4 + q) * 64 + rb) * 8;
    const int lo3 = ((3 * 4 + q) * 64 + rb) * 8;

    for (int dl = 0; dl < 32; ++dl) {
        const int cur = dl & 1;
        if (dl < 31) {   // stage next chunk into other buffer (latency overlaps compute)
            size_t off = (size_t)(dl + 1) * 8192;
            gload16(p0 + off, cur ? d0a : d1a);
            gload16(p1 + off, cur ? d0b : d1b);
        }
        const ushort* sbc = &sB[cur][0];
        f32x4 a0 = (f32x4)0.0f, a1 = (f32x4)0.0f, a2 = (f32x4)0.0f, a3 = (f32x4)0.0f;
        bf16x8 b0_ = *(const bf16x8*)&sbc[lo0];
        bf16x8 b1_ = *(const bf16x8*)&sbc[lo1];
        bf16x8 b2_ = *(const bf16x8*)&sbc[lo2];
        bf16x8 b3_ = *(const bf16x8*)&sbc[lo3];
        __builtin_amdgcn_s_setprio(1);
        {
            a0 = __builtin_amdgcn_mfma_f32_16x16x32_bf16(af[0][0], b0_, a0, 0, 0, 0);
            a1 = __builtin_amdgcn_mfma_f32_16x16x32_bf16(af[1][0], b0_, a1, 0, 0, 0);
            a2 = __builtin_amdgcn_mfma_f32_16x16x32_bf16(af[2][0], b0_, a2, 0, 0, 0);
            a3 = __builtin_amdgcn_mfma_f32_16x16x32_bf16(af[3][0], b0_, a3, 0, 0, 0);
            a0 = __builtin_amdgcn_mfma_f32_16x16x32_bf16(af[0][1], b1_, a0, 0, 0, 0);
            a1 = __builtin_amdgcn_mfma_f32_16x16x32_bf16(af[1][1], b1_, a1, 0, 0, 0);
            a2 = __builtin_amdgcn_mfma_f32_16x16x32_bf16(af[2][1], b1_, a2, 0, 0, 0);
            a3 = __builtin_amdgcn_mfma_f32_16x16x32_bf16(af[3][1], b1_, a3, 0, 0, 0);
            a0 = __builtin_amdgcn_mfma_f32_16x16x32_bf16(af[0][2], b2_, a0, 0, 0, 0);
            a1 = __builtin_amdgcn_mfma_f32_16x16x32_bf16(af[1][2], b2_, a1, 0, 0, 0);
            a2 = __builtin_amdgcn_mfma_f32_16x16x32_bf16(af[2][2], b2_, a2, 0, 0, 0);
            a3 = __builtin_amdgcn_mfma_f32_16x16x32_bf16(af[3][2], b2_, a3, 0, 0, 0);
            a0 = __builtin_amdgcn_mfma_f32_16x16x32_bf16(af[0][3], b3_, a0, 0, 0, 0);
            a1 = __builtin_amdgcn_mfma_f32_16x16x32_bf16(af[1][3], b3_, a1, 0, 0, 0);
            a2 = __builtin_amdgcn_mfma_f32_16x16x32_bf16(af[2][3], b3_, a2, 0, 0, 0);
            a3 = __builtin_amdgcn_mfma_f32_16x16x32_bf16(af[3][3], b3_, a3, 0, 0, 0);
        }
        __builtin_amdgcn_s_setprio(0);
        {
            f32x4 s0 = *(const f32x4*)&soT[dl][eh * 64 + 0 * 16 + q * 4];
            f32x4 s1 = *(const f32x4*)&soT[dl][eh * 64 + 1 * 16 + q * 4];
            f32x4 s2 = *(const f32x4*)&soT[dl][eh * 64 + 2 * 16 + q * 4];
            f32x4 s3 = *(const f32x4*)&soT[dl][eh * 64 + 3 * 16 + q * 4];
#pragma unroll
            for (int j = 0; j < 4; j++) {
                msg[0][j] += a0[j] * s0[j];
                msg[1][j] += a1[j] * s1[j];
                msg[2][j] += a2[j] * s2[j];
                msg[3][j] += a3[j] * s3[j];
            }
        }
        __syncthreads();   // all waves done with sB[cur]; staged prefetch drained
    }

    // ---- add nodeB bias (dh 0 only) and scatter with inv_deg ----
    const int fcol = fs + l15;
#pragma unroll
    for (int mi = 0; mi < 4; mi++) {
#pragma unroll
        for (int j = 0; j < 4; j++) {
            int er = eh * 64 + mi * 16 + q * 4 + j;
            float v = msg[mi][j];
            if (dh == 0) v += rgh[(size_t)sSrc[er] * 320 + 256 + fcol];
            atomicAdd(&agg[(size_t)sDst[er] * 64 + fcol], v * sIv[er]);
        }
    }
}

// ---------------- rgh = outN @ Bcat.T + bcat  [N][320]; also zeroes agg ----------------
__global__ __launch_bounds__(256) void k_rgh(const float* __restrict__ A,
                                             const float* __restrict__ Bm,
                                             const float* __restrict__ bias,
                                             float* __restrict__ C,
                                             float* __restrict__ aggz) {
    const int tid = threadIdx.x;
    const int bx = blockIdx.x, by = blockIdx.y;   // grid (5, 128)
    {
        int bid = by * 5 + bx;
        if (bid < 512) {
            float4 z; z.x = z.y = z.z = z.w = 0.0f;
            *(float4*)(aggz + (size_t)bid * 1024 + tid * 4) = z;
        }
    }
    __shared__ float sA[64 * 68];
    __shared__ float sB[64 * 68];
    const float* Ab = A + (size_t)by * 64 * 64;
    const float* Bb = Bm + (size_t)bx * 64 * 64;
    for (int fi = tid; fi < 64 * 16; fi += 256) {
        int r = fi >> 4, c = (fi & 15) * 4;
        *(float4*)&sA[r * 68 + c] = *(const float4*)(Ab + (size_t)r * 64 + c);
        *(float4*)&sB[r * 68 + c] = *(const float4*)(Bb + (size_t)r * 64 + c);
    }
    __syncthreads();
    const int tx = tid & 15, ty = tid >> 4;
    float acc[4][4];
#pragma unroll
    for (int i = 0; i < 4; i++)
#pragma unroll
        for (int j = 0; j < 4; j++) acc[i][j] = 0.0f;
    for (int k = 0; k < 64; k += 4) {
        float4 av[4], bv[4];
#pragma unroll
        for (int i = 0; i < 4; i++) av[i] = *(const float4*)&sA[(ty + 16 * i) * 68 + k];
#pragma unroll
        for (int j = 0; j < 4; j++) bv[j] = *(const float4*)&sB[(tx + 16 * j) * 68 + k];
#pragma unroll
        for (int i = 0; i < 4; i++)
#pragma unroll
            for (int j = 0; j < 4; j++) {
                acc[i][j] += av[i].x * bv[j].x;
                acc[i][j] += av[i].y * bv[j].y;
                acc[i][j] += av[i].z * bv[j].z;
                acc[i][j] += av[i].w * bv[j].w;
            }
    }
#pragma unroll
    for (int i = 0; i < 4; i++) {
        size_t row = (size_t)by * 64 + ty + 16 * i;
#pragma unroll
        for (int j = 0; j < 4; j++) {
            int col = bx * 64 + tx + 16 * j;
            C[row * 320 + col] = acc[i][j] + bias[col];
        }
    }
}

// ---------------- fused gx GEMM (m = relu(agg+rootC+cb) staged) + GRU update ----------------
__global__ __launch_bounds__(256) void k_gxgru(const float* __restrict__ agg,
                                               const float* __restrict__ rgh,
                                               const float* __restrict__ cb,
                                               const float* __restrict__ wih,   // gru_w_ih [192][64]
                                               const float* __restrict__ bih,
                                               float* __restrict__ outN) {
    __shared__ float sA[64 * 68];
    __shared__ float sB[192 * 68];
    const int t = threadIdx.x;
    const int by = blockIdx.x;
    for (int fi = t; fi < 64 * 16; fi += 256) {
        int r = fi >> 4, c = (fi & 15) * 4;
        float4 av = *(const float4*)(agg + (size_t)(by * 64 + r) * 64 + c);
        float4 rv = *(const float4*)(rgh + (size_t)(by * 64 + r) * 320 + c);
        float4 cv = *(const float4*)(cb + c);
        float4 m;
        m.x = fmaxf(av.x + rv.x + cv.x, 0.0f);
        m.y = fmaxf(av.y + rv.y + cv.y, 0.0f);
        m.z = fmaxf(av.z + rv.z + cv.z, 0.0f);
        m.w = fmaxf(av.w + rv.w + cv.w, 0.0f);
        *(float4*)&sA[r * 68 + c] = m;
    }
    for (int fi = t; fi < 192 * 16; fi += 256) {
        int r = fi >> 4, c = (fi & 15) * 4;
        *(float4*)&sB[r * 68 + c] = *(const float4*)(wih + (size_t)r * 64 + c);
    }
    __syncthreads();
    const int tx = t & 15, ty = t >> 4;
    float acc[3][4][4];
#pragma unroll
    for (int cx = 0; cx < 3; cx++)
#pragma unroll
        for (int i = 0; i < 4; i++)
#pragma unroll
            for (int j = 0; j < 4; j++) acc[cx][i][j] = 0.0f;
    for (int k = 0; k < 64; k += 4) {
        float4 av[4];
#pragma unroll
        for (int i = 0; i < 4; i++) av[i] = *(const float4*)&sA[(ty + 16 * i) * 68 + k];
#pragma unroll
        for (int cx = 0; cx < 3; cx++) {
            float4 bv[4];
#pragma unroll
            for (int j = 0; j < 4; j++) bv[j] = *(const float4*)&sB[(cx * 64 + tx + 16 * j) * 68 + k];
#pragma unroll
            for (int i = 0; i < 4; i++)
#pragma unroll
                for (int j = 0; j < 4; j++) {
                    acc[cx][i][j] += av[i].x * bv[j].x;
                    acc[cx][i][j] += av[i].y * bv[j].y;
                    acc[cx][i][j] += av[i].z * bv[j].z;
                    acc[cx][i][j] += av[i].w * bv[j].w;
                }
        }
    }
#pragma unroll
    for (int i = 0; i < 4; i++) {
        int n = by * 64 + ty + 16 * i;
        const float* ghr = rgh + (size_t)n * 320 + 64;
#pragma unroll
        for (int j = 0; j < 4; j++) {
            int d = tx + 16 * j;
            float r = sigmoidf_(acc[0][i][j] + bih[d] + ghr[d]);
            float z = sigmoidf_(acc[1][i][j] + bih[64 + d] + ghr[64 + d]);
            float nn_ = tanhf(acc[2][i][j] + bih[128 + d] + r * ghr[128 + d]);
            float hp = outN[(size_t)n * 64 + d];
            outN[(size_t)n * 64 + d] = (1.0f - z) * nn_ + z * hp;
        }
    }
}

// ---------------- fused Set2Set (3 steps) + head: one block per graph ----------------
__global__ __launch_bounds__(256) void k_s2sall(const float* __restrict__ outN,
                                                const int* __restrict__ offs,
                                                const float* __restrict__ wihT,
                                                const float* __restrict__ whhT,
                                                const float* __restrict__ bih,
                                                const float* __restrict__ bhh,
                                                const float* __restrict__ lin1_w,
                                                const float* __restrict__ lin1_b,
                                                const float* __restrict__ lin2_w,
                                                const float* __restrict__ lin2_b,
                                                float* __restrict__ earr,
                                                float* __restrict__ y) {
    const int b = blockIdx.x, t = threadIdx.x;
    const int w = t >> 6, l = t & 63;
    __shared__ float qs[128], qhL[64], qcL[64], gates[256];
    __shared__ float red[8];
    __shared__ float rpart[4][64];
    __shared__ float hbuf[64];
    const int s0 = offs[b], s1 = offs[b + 1];
    if (t < 128) qs[t] = 0.0f;
    if (t < 64) { qhL[t] = 0.0f; qcL[t] = 0.0f; }
    __syncthreads();

    for (int st = 0; st < 3; st++) {
        float g = bih[t] + bhh[t];
        for (int k = 0; k < 128; k++) g += qs[k] * wihT[k * 256 + t];
        for (int k = 0; k < 64; k++) g += qhL[k] * whhT[k * 256 + t];
        gates[t] = g;
        __syncthreads();
        if (t < 64) {
            float gi = gates[t], gf = gates[64 + t], gg = gates[128 + t], go = gates[192 + t];
            float c = sigmoidf_(gf) * qcL[t] + sigmoidf_(gi) * tanhf(gg);
            qcL[t] = c;
            qhL[t] = sigmoidf_(go) * tanhf(c);
        }
        __syncthreads();
        float mx = -INFINITY;
        for (int i = s0 + w; i < s1; i += 4) {
            float p = outN[(size_t)i * 64 + l] * qhL[l];
#pragma unroll
            for (int o = 32; o > 0; o >>= 1) p += __shfl_xor(p, o, 64);
            if (l == 0) earr[i] = p;
            mx = fmaxf(mx, p);
        }
        if (l == 0) red[w] = mx;
        __syncthreads();
        mx = fmaxf(fmaxf(red[0], red[1]), fmaxf(red[2], red[3]));
        if (!isfinite(mx)) mx = 0.0f;
        float sm = 0.0f, racc = 0.0f;
        for (int i = s0 + w; i < s1; i += 4) {
            float a = expf(earr[i] - mx);
            sm += a;
            racc += a * outN[(size_t)i * 64 + l];
        }
        rpart[w][l] = racc;
        if (l == 0) red[4 + w] = sm;
        __syncthreads();
        float smT = fmaxf(red[4] + red[5] + red[6] + red[7], 1e-12f);
        if (t < 64) {
            float r = (rpart[0][t] + rpart[1][t] + rpart[2][t] + rpart[3][t]) / smT;
            qs[t] = qhL[t];
            qs[64 + t] = r;
        }
        __syncthreads();
    }
    if (t < 64) {
        float h = lin1_b[t];
        for (int k = 0; k < 128; k++) h += qs[k] * lin1_w[t * 128 + k];
        hbuf[t] = fmaxf(h, 0.0f) * lin2_w[t];
    }
    __syncthreads();
    if (w == 0) {
        float p = hbuf[l];
#pragma unroll
        for (int o = 32; o > 0; o >>= 1) p += __shfl_xor(p, o, 64);
        if (l == 0) y[b] = p + lin2_b[0];
    }
}

extern "C" void kernel_launch(void* const* d_in, const int* in_sizes, int n_in,
                              void* d_out, int out_size, void* d_ws, size_t ws_size,
                              hipStream_t stream) {
    const float* x = (const float*)d_in[0];
    const float* edge_attr = (const float*)d_in[1];
    const float* lin0_w = (const float*)d_in[2];
    const float* lin0_b = (const float*)d_in[3];
    const float* nn1_w = (const float*)d_in[4];
    const float* nn1_b = (const float*)d_in[5];
    const float* nn2_w = (const float*)d_in[6];
    const float* nn2_b = (const float*)d_in[7];
    const float* root_w = (const float*)d_in[8];
    const float* conv_b = (const float*)d_in[9];
    const float* gru_w_ih = (const float*)d_in[10];
    const float* gru_w_hh = (const float*)d_in[11];
    const float* gru_b_ih = (const float*)d_in[12];
    const float* gru_b_hh = (const float*)d_in[13];
    const float* s2s_w_ih = (const float*)d_in[14];
    const float* s2s_w_hh = (const float*)d_in[15];
    const float* s2s_b_ih = (const float*)d_in[16];
    const float* s2s_b_hh = (const float*)d_in[17];
    const float* lin1_w = (const float*)d_in[18];
    const float* lin1_b = (const float*)d_in[19];
    const float* lin2_w = (const float*)d_in[20];
    const float* lin2_b = (const float*)d_in[21];
    const int* ei = (const int*)d_in[22];
    const int* batch = (const int*)d_in[23];
    float* outp = (float*)d_out;

    char* w = (char*)d_ws;
    auto carve = [&](size_t bytes) { char* p = w; w += (bytes + 255) & ~(size_t)255; return p; };
    __hip_bfloat16* nn2T = (__hip_bfloat16*)carve((size_t)4096 * 128 * 2);
    float* outN = (float*)carve((size_t)NN * 64 * 4);
    __hip_bfloat16* h1 = (__hip_bfloat16*)carve((size_t)EE * 128 * 2);
    int* deg = (int*)carve(NN * 4);
    float* invd = (float*)carve(NN * 4);
    float* agg = (float*)carve((size_t)NN * 64 * 4);
    float* rgh = (float*)carve((size_t)NN * 320 * 4);
    float* Bcat = (float*)carve((size_t)320 * 64 * 4);
    float* bcat = (float*)carve(320 * 4);
    float* wihT = (float*)carve((size_t)128 * 256 * 4);
    float* whhT = (float*)carve((size_t)64 * 256 * 4);
    float* earr = (float*)carve(NN * 4);
    int* cnt = (int*)carve(256 * 4);
    int* offs = (int*)carve(257 * 4);

    hipMemsetAsync(deg, 0, NN * 4, stream);
    hipMemsetAsync(cnt, 0, 256 * 4, stream);

    k_setup<<<5264, 256, 0, stream>>>(x, edge_attr, lin0_w, lin0_b, nn1_w, nn1_b,
                                      nn2_w, nn2_b, root_w, gru_w_hh, gru_b_hh,
                                      s2s_w_ih, s2s_w_hh, ei, batch,
                                      h1, outN, nn2T, wihT, whhT, Bcat, bcat, deg, cnt);
    k_invscan<<<33, 256, 0, stream>>>(deg, invd, cnt, offs);

    for (int it = 0; it < 3; it++) {
        k_rgh<<<dim3(5, NN / 64), 256, 0, stream>>>(outN, Bcat, bcat, rgh, agg);
        k_wemsg<<<EE / 64, 512, 0, stream>>>(h1, nn2T, outN, rgh, ei, invd, agg);
        k_gxgru<<<NN / 64, 256, 0, stream>>>(agg, rgh, conv_b, gru_w_ih, gru_b_ih, outN);
    }

    k_s2sall<<<BB, 256, 0, stream>>>(outN, offs, wihT, whhT, s2s_b_ih, s2s_b_hh,
                                     lin1_w, lin1_b, lin2_w, lin2_b, earr, outp);
}